// Round 7
// baseline (192.490 us; speedup 1.0000x reference)
//
#include <hip/hip_runtime.h>
#include <stdint.h>

#define T_ROWS 8192
#define IN_F 4096
#define OUT_F 4096

using i32x4 = __attribute__((ext_vector_type(4))) int;
using i32x16 = __attribute__((ext_vector_type(16))) int;

#define GLOBAL_AS __attribute__((address_space(1)))
#define LDS_AS __attribute__((address_space(3)))

static __device__ __forceinline__ void load_lds16(const void* g, void* l) {
    __builtin_amdgcn_global_load_lds((const GLOBAL_AS uint32_t*)g,
                                     (LDS_AS uint32_t*)l, 16, 0, 0);
}

// -------- Kernel 1: fused prep: per-row int8 quant (blocks 0..8191) +
//                    ternary f32 -> int8 weight pack (blocks 8192..12287) --------
__global__ __launch_bounds__(256) void prep_kernel(const float* __restrict__ x,
                                                   int8_t* __restrict__ xq,
                                                   float* __restrict__ scales,
                                                   const float* __restrict__ w,
                                                   int8_t* __restrict__ w8) {
    if (blockIdx.x < T_ROWS) {
        const int row = blockIdx.x;
        const float* xr = x + (size_t)row * IN_F;
        const float4* xr4 = (const float4*)xr;

        float4 v[4];
        float amax = 0.0f;
#pragma unroll
        for (int i = 0; i < 4; ++i) {
            v[i] = xr4[threadIdx.x + 256 * i];
            amax = fmaxf(amax, fmaxf(fmaxf(fabsf(v[i].x), fabsf(v[i].y)),
                                     fmaxf(fabsf(v[i].z), fabsf(v[i].w))));
        }
#pragma unroll
        for (int off = 32; off; off >>= 1)
            amax = fmaxf(amax, __shfl_xor(amax, off, 64));
        __shared__ float smax[4];
        if ((threadIdx.x & 63) == 0) smax[threadIdx.x >> 6] = amax;
        __syncthreads();
        amax = fmaxf(fmaxf(smax[0], smax[1]), fmaxf(smax[2], smax[3]));

        const float act_scale = fmaxf(amax, 1e-10f) / 127.0f;
        if (threadIdx.x == 0) scales[row] = act_scale;

        int* xqr = (int*)(xq + (size_t)row * IN_F);
#pragma unroll
        for (int i = 0; i < 4; ++i) {
            int q0 = (int)fminf(fmaxf(rintf(v[i].x / act_scale), -127.0f), 127.0f);
            int q1 = (int)fminf(fmaxf(rintf(v[i].y / act_scale), -127.0f), 127.0f);
            int q2 = (int)fminf(fmaxf(rintf(v[i].z / act_scale), -127.0f), 127.0f);
            int q3 = (int)fminf(fmaxf(rintf(v[i].w / act_scale), -127.0f), 127.0f);
            int packed = (q0 & 0xff) | ((q1 & 0xff) << 8) | ((q2 & 0xff) << 16) | (q3 << 24);
            xqr[threadIdx.x + 256 * i] = packed;
        }
    } else {
        const float4* w4 = (const float4*)w;
        int* o4 = (int*)w8;
        size_t base = (size_t)(blockIdx.x - T_ROWS) * 1024 + threadIdx.x;
#pragma unroll
        for (int i = 0; i < 4; ++i) {
            size_t idx = base + 256 * i;
            float4 v = w4[idx];
            int q0 = (int)v.x, q1 = (int)v.y, q2 = (int)v.z, q3 = (int)v.w;
            o4[idx] = (q0 & 0xff) | ((q1 & 0xff) << 8) | ((q2 & 0xff) << 16) | (q3 << 24);
        }
    }
}

// ---------- Kernel 2: 256x256 software-pipelined 32x32x32-i8 MFMA GEMM ----------
// C[t][o] = sum_k xq[t][k] * w8[o][k]   (NT: both row-major, K contiguous)
// 512 threads = 8 waves (2M x 4N). Per-wave output 128x64 contiguous:
//   rows = wr*128 + mi*32 (mi=0..3), cols = wc*64 + ni*32 (ni=0..1).
// LDS: row-major [buf 2][row 256][128B] per matrix, XOR-swizzled (slot^= r&7);
// staging identical to rounds 4-6 (linear dest, pre-swizzled source).
// PIPELINE: phase = one K-step (K=32). Phase p issues 6 ds_read_b128 for
// phase p+1's fragments (ping-pong sets a0/b0 vs a1/b1, 24 VGPR each), then
// runs 8 independent 32x32x32 MFMAs on registers loaded LAST phase. Compiler
// emits lgkmcnt(6): waits only the older reads -> this phase's reads drain
// under this phase's MFMAs (LDS || MFMA overlap, breaking the serial sum).
// Barriers only where staging hazards cross (4 per 8 phases):
//   stages: buf1 <- p1 (A0,A1,B0) + p2 (B1); buf0 <- p5 (A0,A1,B0) + p6 (B1)
//   end-p3: vmcnt(0)+barrier  (buf1 stages drained before p4's buf1 prefetch)
//   end-p4: barrier           (all buf0 reads consumed before p5's restage)
//   end-p7: vmcnt(0)+barrier  (buf0 stages drained before p8's buf0 prefetch)
//   end-p8: barrier           (all buf1 reads consumed before p1's restage)
// Free-run regions p1-p3 / p5-p7 read one buffer and stage the other ->
// wave slip is safe; vmcnt(0) retires loads issued 1-2 phases (~1400 cyc) ago.
__global__ __launch_bounds__(512, 2) void gemm_kernel(const int8_t* __restrict__ xq,
                                                      const int8_t* __restrict__ w8,
                                                      const float* __restrict__ scales,
                                                      const float* __restrict__ bias,
                                                      const float* __restrict__ wscale_p,
                                                      float* __restrict__ out) {
    __shared__ __align__(16) int8_t As[2 * 256 * 128];  // 64 KiB
    __shared__ __align__(16) int8_t Bs[2 * 256 * 128];  // 64 KiB

    const int tid = threadIdx.x;
    const int lane = tid & 63;
    const int w = tid >> 6;     // wave 0..7
    const int wr = w >> 2;      // 0..1
    const int wc = w & 3;       // 0..3
    const int l31 = lane & 31;
    const int lh = lane >> 5;   // 0..1: K-half within a fragment
    const int le = lane & 7;

    // XCD-aware swizzle: nwg=512 (divisible by 8), contiguous chunk of 64 per XCD.
    int bid = blockIdx.x;
    bid = (bid & 7) * 64 + (bid >> 3);
    const int brow = (bid >> 4) * 256;
    const int bcol = (bid & 15) * 256;

    // per-lane staging source: row +(lane>>3), K-slot (lane&7)^(lane>>3)
    const int lrow = lane >> 3;
    const int lslot = (lane & 7) ^ lrow;
    const int8_t* srcA = xq + (size_t)(brow + lrow) * IN_F + lslot * 16;
    const int8_t* srcB = w8 + (size_t)(bcol + lrow) * IN_F + lslot * 16;

    // Fragment read addressing. A-frag (mi,ks): lane reads row wr*128+mi*32+l31,
    // global 16B-chunk ks*2+lh; LDS slot = chunk ^ (row&7), and row&7 == le for
    // both A and B (mi*32, wr*128, ni*32, wc*64 all ≡ 0 mod 8).
    const int aBase = (wr * 128 + l31) * 128;
    const int bBase = (wc * 64 + l31) * 128;
    const int slo[4] = { ((0 + lh) ^ le) << 4, ((2 + lh) ^ le) << 4,
                         ((4 + lh) ^ le) << 4, ((6 + lh) ^ le) << 4 };

#define STAGE(LDSA, SRC, BUF, H, KT) do {                                          \
    load_lds16((SRC) + (size_t)((H) * 128 + w * 8) * IN_F + (KT) * 128,            \
               (void*)((LDSA) + (BUF) * 32768 + ((H) * 16 + w) * 1024));           \
    load_lds16((SRC) + (size_t)((H) * 128 + (w + 8) * 8) * IN_F + (KT) * 128,      \
               (void*)((LDSA) + (BUF) * 32768 + ((H) * 16 + w + 8) * 1024));       \
} while (0)

#define PF(FA, FB, BUF, KS) do {                                                   \
    _Pragma("unroll") for (int mi = 0; mi < 4; ++mi)                               \
        FA[mi] = *(const i32x4*)(As + (BUF) * 32768 + aBase + mi * 4096 + slo[KS]);\
    _Pragma("unroll") for (int ni = 0; ni < 2; ++ni)                               \
        FB[ni] = *(const i32x4*)(Bs + (BUF) * 32768 + bBase + ni * 4096 + slo[KS]);\
} while (0)

#define MFMA8(FA, FB) do {                                                         \
    __builtin_amdgcn_s_setprio(1);                                                 \
    _Pragma("unroll") for (int mi = 0; mi < 4; ++mi)                               \
    _Pragma("unroll") for (int ni = 0; ni < 2; ++ni)                               \
        acc[mi][ni] = __builtin_amdgcn_mfma_i32_32x32x32_i8(FA[mi], FB[ni],        \
                                                            acc[mi][ni], 0, 0, 0); \
    __builtin_amdgcn_s_setprio(0);                                                 \
} while (0)

#define BARFENCE do { __builtin_amdgcn_s_barrier(); asm volatile("" ::: "memory"); } while (0)
#define VM0 asm volatile("s_waitcnt vmcnt(0)" ::: "memory")

    i32x16 acc[4][2] = {};
    i32x4 a0[4], b0[2], a1[4], b1[2];

    // Prologue: buf0 <- K-tile 0 (all 4 halves); drain; prefetch first frags.
    STAGE(As, srcA, 0, 0, 0);
    STAGE(As, srcA, 0, 1, 0);
    STAGE(Bs, srcB, 0, 0, 0);
    STAGE(Bs, srcB, 0, 1, 0);
    VM0;
    BARFENCE;
    PF(a0, b0, 0, 0);

    for (int t = 0; t < 16; ++t) {
        const int k1 = (2 * t + 1) & 31;
        const int k2 = (2 * t + 2) & 31;  // wraps on last iter: dead-but-safe stages
        // p1
        PF(a1, b1, 0, 1);
        STAGE(As, srcA, 1, 0, k1);
        STAGE(As, srcA, 1, 1, k1);
        STAGE(Bs, srcB, 1, 0, k1);
        MFMA8(a0, b0);
        // p2
        PF(a0, b0, 0, 2);
        STAGE(Bs, srcB, 1, 1, k1);
        MFMA8(a1, b1);
        // p3
        PF(a1, b1, 0, 3);
        MFMA8(a0, b0);
        VM0;
        BARFENCE;
        // p4
        PF(a0, b0, 1, 0);
        MFMA8(a1, b1);
        BARFENCE;
        // p5
        PF(a1, b1, 1, 1);
        STAGE(As, srcA, 0, 0, k2);
        STAGE(As, srcA, 0, 1, k2);
        STAGE(Bs, srcB, 0, 0, k2);
        MFMA8(a0, b0);
        // p6
        PF(a0, b0, 1, 2);
        STAGE(Bs, srcB, 0, 1, k2);
        MFMA8(a1, b1);
        // p7
        PF(a1, b1, 1, 3);
        MFMA8(a0, b0);
        VM0;
        BARFENCE;
        // p8
        PF(a0, b0, 0, 0);
        MFMA8(a1, b1);
        BARFENCE;
    }

    // Epilogue: 32x32 C/D map (verified m74/m101, dtype-independent):
    //   col = lane&31, row = (reg&3) + 8*(reg>>2) + 4*(lane>>5), reg = q*4+r.
    const float ws = wscale_p[0];
#pragma unroll
    for (int mi = 0; mi < 4; ++mi) {
#pragma unroll
        for (int q = 0; q < 4; ++q) {
#pragma unroll
            for (int r = 0; r < 4; ++r) {
                const int row = brow + wr * 128 + mi * 32 + q * 8 + r + 4 * lh;
                const float sc = scales[row] * ws;
#pragma unroll
                for (int ni = 0; ni < 2; ++ni) {
                    const int col = bcol + wc * 64 + ni * 32 + l31;
                    out[(size_t)row * OUT_F + col] =
                        (float)acc[mi][ni][q * 4 + r] * sc + bias[col];
                }
            }
        }
    }
#undef STAGE
#undef PF
#undef MFMA8
#undef BARFENCE
#undef VM0
}

extern "C" void kernel_launch(void* const* d_in, const int* in_sizes, int n_in,
                              void* d_out, int out_size, void* d_ws, size_t ws_size,
                              hipStream_t stream) {
    const float* x       = (const float*)d_in[0];
    const float* w_t     = (const float*)d_in[1];
    const float* w_scale = (const float*)d_in[2];
    const float* bias    = (const float*)d_in[3];
    float* out = (float*)d_out;

    int8_t* xq     = (int8_t*)d_ws;
    float*  scales = (float*)((char*)d_ws + (size_t)T_ROWS * IN_F);
    int8_t* w8     = (int8_t*)((char*)d_ws + (size_t)T_ROWS * IN_F + T_ROWS * sizeof(float));

    prep_kernel<<<T_ROWS + (OUT_F * IN_F) / (16 * 256), 256, 0, stream>>>(
        x, xq, scales, w_t, w8);

    gemm_kernel<<<(T_ROWS / 256) * (OUT_F / 256), 512, 0, stream>>>(
        xq, w8, scales, bias, w_scale, out);
}

// Round 8
// 191.729 us; speedup vs baseline: 1.0040x; 1.0040x over previous
//
#include <hip/hip_runtime.h>
#include <stdint.h>

#define T_ROWS 8192
#define IN_F 4096
#define OUT_F 4096

using i32x4 = __attribute__((ext_vector_type(4))) int;
using i32x16 = __attribute__((ext_vector_type(16))) int;

#define GLOBAL_AS __attribute__((address_space(1)))
#define LDS_AS __attribute__((address_space(3)))

static __device__ __forceinline__ void load_lds16(const void* g, void* l) {
    __builtin_amdgcn_global_load_lds((const GLOBAL_AS uint32_t*)g,
                                     (LDS_AS uint32_t*)l, 16, 0, 0);
}

// -------- Kernel 1: fused prep: per-row int8 quant (blocks 0..8191) +
//                    ternary f32 -> int8 weight pack (blocks 8192..12287) --------
__global__ __launch_bounds__(256) void prep_kernel(const float* __restrict__ x,
                                                   int8_t* __restrict__ xq,
                                                   float* __restrict__ scales,
                                                   const float* __restrict__ w,
                                                   int8_t* __restrict__ w8) {
    if (blockIdx.x < T_ROWS) {
        const int row = blockIdx.x;
        const float* xr = x + (size_t)row * IN_F;
        const float4* xr4 = (const float4*)xr;

        float4 v[4];
        float amax = 0.0f;
#pragma unroll
        for (int i = 0; i < 4; ++i) {
            v[i] = xr4[threadIdx.x + 256 * i];
            amax = fmaxf(amax, fmaxf(fmaxf(fabsf(v[i].x), fabsf(v[i].y)),
                                     fmaxf(fabsf(v[i].z), fabsf(v[i].w))));
        }
#pragma unroll
        for (int off = 32; off; off >>= 1)
            amax = fmaxf(amax, __shfl_xor(amax, off, 64));
        __shared__ float smax[4];
        if ((threadIdx.x & 63) == 0) smax[threadIdx.x >> 6] = amax;
        __syncthreads();
        amax = fmaxf(fmaxf(smax[0], smax[1]), fmaxf(smax[2], smax[3]));

        const float act_scale = fmaxf(amax, 1e-10f) / 127.0f;
        if (threadIdx.x == 0) scales[row] = act_scale;

        int* xqr = (int*)(xq + (size_t)row * IN_F);
#pragma unroll
        for (int i = 0; i < 4; ++i) {
            int q0 = (int)fminf(fmaxf(rintf(v[i].x / act_scale), -127.0f), 127.0f);
            int q1 = (int)fminf(fmaxf(rintf(v[i].y / act_scale), -127.0f), 127.0f);
            int q2 = (int)fminf(fmaxf(rintf(v[i].z / act_scale), -127.0f), 127.0f);
            int q3 = (int)fminf(fmaxf(rintf(v[i].w / act_scale), -127.0f), 127.0f);
            int packed = (q0 & 0xff) | ((q1 & 0xff) << 8) | ((q2 & 0xff) << 16) | (q3 << 24);
            xqr[threadIdx.x + 256 * i] = packed;
        }
    } else {
        const float4* w4 = (const float4*)w;
        int* o4 = (int*)w8;
        size_t base = (size_t)(blockIdx.x - T_ROWS) * 1024 + threadIdx.x;
#pragma unroll
        for (int i = 0; i < 4; ++i) {
            size_t idx = base + 256 * i;
            float4 v = w4[idx];
            int q0 = (int)v.x, q1 = (int)v.y, q2 = (int)v.z, q3 = (int)v.w;
            o4[idx] = (q0 & 0xff) | ((q1 & 0xff) << 8) | ((q2 & 0xff) << 16) | (q3 << 24);
        }
    }
}

// ---------- Kernel 2: 256x256 software-pipelined 32x32x32-i8 MFMA GEMM ----------
// Structure as round 7 (ping-pong fragment prefetch, 4 barriers / 8 phases),
// plus: (1) sched_barrier(0) pinning so the scheduler cannot sink a phase's
// ds_reads below its MFMA block (rule #18-style: explicit lgkmcnt(6) waits
// only the PREVIOUS phase's 6 reads; global_load_lds counts in vmcnt, not
// lgkm); (2) swizzle extended to S(r) = (r&7) ^ (((r>>5)&1)<<2) so adjacent
// fragment reads (mi / ni parity) hit disjoint bank halves.
__global__ __launch_bounds__(512, 2) void gemm_kernel(const int8_t* __restrict__ xq,
                                                      const int8_t* __restrict__ w8,
                                                      const float* __restrict__ scales,
                                                      const float* __restrict__ bias,
                                                      const float* __restrict__ wscale_p,
                                                      float* __restrict__ out) {
    __shared__ __align__(16) int8_t As[2 * 256 * 128];  // 64 KiB
    __shared__ __align__(16) int8_t Bs[2 * 256 * 128];  // 64 KiB

    const int tid = threadIdx.x;
    const int lane = tid & 63;
    const int w = tid >> 6;     // wave 0..7
    const int wr = w >> 2;      // 0..1
    const int wc = w & 3;       // 0..3
    const int l31 = lane & 31;
    const int lh = lane >> 5;   // 0..1: K-half within a fragment
    const int le = lane & 7;

    // XCD-aware swizzle: nwg=512 (divisible by 8), contiguous chunk of 64 per XCD.
    int bid = blockIdx.x;
    bid = (bid & 7) * 64 + (bid >> 3);
    const int brow = (bid >> 4) * 256;
    const int bcol = (bid & 15) * 256;

    // per-lane staging source with S(r) = (r&7) ^ (((r>>5)&1)<<2):
    // lane l writes LDS slot (l&7) of row base+(l>>3); base>>5 bit0 = (w>>2)&1
    // for both of the wave's 8-row regions -> per-wave constant XOR.
    const int lrow = lane >> 3;
    const int lslot = (lane & 7) ^ lrow ^ (((w >> 2) & 1) << 2);
    const int8_t* srcA = xq + (size_t)(brow + lrow) * IN_F + lslot * 16;
    const int8_t* srcB = w8 + (size_t)(bcol + lrow) * IN_F + lslot * 16;

    // Fragment read addressing: A-frag (mi,ks): row = wr*128+mi*32+l31, global
    // chunk 2ks+lh, LDS slot = chunk ^ (row&7) ^ ((row>>5)&1)<<2; row&7 = le,
    // (row>>5)&1 = mi&1 (A) / ni&1 (B) -> compile-time ^64 on byte offset.
    const int aBase = (wr * 128 + l31) * 128;
    const int bBase = (wc * 64 + l31) * 128;
    const int slo[4] = { ((0 + lh) ^ le) << 4, ((2 + lh) ^ le) << 4,
                         ((4 + lh) ^ le) << 4, ((6 + lh) ^ le) << 4 };

#define STAGE(LDSA, SRC, BUF, H, KT) do {                                          \
    load_lds16((SRC) + (size_t)((H) * 128 + w * 8) * IN_F + (KT) * 128,            \
               (void*)((LDSA) + (BUF) * 32768 + ((H) * 16 + w) * 1024));           \
    load_lds16((SRC) + (size_t)((H) * 128 + (w + 8) * 8) * IN_F + (KT) * 128,      \
               (void*)((LDSA) + (BUF) * 32768 + ((H) * 16 + w + 8) * 1024));       \
} while (0)

#define PF(FA, FB, BUF, KS) do {                                                   \
    _Pragma("unroll") for (int mi = 0; mi < 4; ++mi)                               \
        FA[mi] = *(const i32x4*)(As + (BUF) * 32768 + aBase + mi * 4096 +          \
                                 (slo[KS] ^ ((mi & 1) << 6)));                     \
    _Pragma("unroll") for (int ni = 0; ni < 2; ++ni)                               \
        FB[ni] = *(const i32x4*)(Bs + (BUF) * 32768 + bBase + ni * 4096 +          \
                                 (slo[KS] ^ ((ni & 1) << 6)));                     \
} while (0)

#define MFMA8(FA, FB) do {                                                         \
    __builtin_amdgcn_s_setprio(1);                                                 \
    _Pragma("unroll") for (int mi = 0; mi < 4; ++mi)                               \
    _Pragma("unroll") for (int ni = 0; ni < 2; ++ni)                               \
        acc[mi][ni] = __builtin_amdgcn_mfma_i32_32x32x32_i8(FA[mi], FB[ni],        \
                                                            acc[mi][ni], 0, 0, 0); \
    __builtin_amdgcn_s_setprio(0);                                                 \
} while (0)

// Pinned phase: reads+stages issue first, explicit wait retires only the
// PREVIOUS phase's 6 ds_reads, MFMAs run while this phase's reads drain.
#define PHASE(PFS, STAGES, FA, FB) do {                                            \
    PFS;                                                                           \
    STAGES;                                                                        \
    __builtin_amdgcn_sched_barrier(0);                                             \
    asm volatile("s_waitcnt lgkmcnt(6)" ::: "memory");                             \
    __builtin_amdgcn_sched_barrier(0);                                             \
    MFMA8(FA, FB);                                                                 \
    __builtin_amdgcn_sched_barrier(0);                                             \
} while (0)

#define BARFENCE do { __builtin_amdgcn_s_barrier(); asm volatile("" ::: "memory"); } while (0)
#define VM0 asm volatile("s_waitcnt vmcnt(0)" ::: "memory")

    i32x16 acc[4][2] = {};
    i32x4 a0[4], b0[2], a1[4], b1[2];

    // Prologue: buf0 <- K-tile 0 (all 4 halves); drain; prefetch first frags.
    STAGE(As, srcA, 0, 0, 0);
    STAGE(As, srcA, 0, 1, 0);
    STAGE(Bs, srcB, 0, 0, 0);
    STAGE(Bs, srcB, 0, 1, 0);
    VM0;
    BARFENCE;
    PF(a0, b0, 0, 0);

    for (int t = 0; t < 16; ++t) {
        const int k1 = (2 * t + 1) & 31;
        const int k2 = (2 * t + 2) & 31;  // wraps on last iter: dead-but-safe stages
        // p1
        PHASE(PF(a1, b1, 0, 1),
              STAGE(As, srcA, 1, 0, k1); STAGE(As, srcA, 1, 1, k1);
              STAGE(Bs, srcB, 1, 0, k1),
              a0, b0);
        // p2
        PHASE(PF(a0, b0, 0, 2), STAGE(Bs, srcB, 1, 1, k1), a1, b1);
        // p3
        PHASE(PF(a1, b1, 0, 3), , a0, b0);
        VM0;
        BARFENCE;
        // p4
        PHASE(PF(a0, b0, 1, 0), , a1, b1);
        BARFENCE;
        // p5
        PHASE(PF(a1, b1, 1, 1),
              STAGE(As, srcA, 0, 0, k2); STAGE(As, srcA, 0, 1, k2);
              STAGE(Bs, srcB, 0, 0, k2),
              a0, b0);
        // p6
        PHASE(PF(a0, b0, 1, 2), STAGE(Bs, srcB, 0, 1, k2), a1, b1);
        // p7
        PHASE(PF(a1, b1, 1, 3), , a0, b0);
        VM0;
        BARFENCE;
        // p8
        PHASE(PF(a0, b0, 0, 0), , a1, b1);
        BARFENCE;
    }

    // Epilogue: 32x32 C/D map (verified m74/m101, dtype-independent):
    //   col = lane&31, row = (reg&3) + 8*(reg>>2) + 4*(lane>>5), reg = q*4+r.
    const float ws = wscale_p[0];
#pragma unroll
    for (int mi = 0; mi < 4; ++mi) {
#pragma unroll
        for (int q = 0; q < 4; ++q) {
#pragma unroll
            for (int r = 0; r < 4; ++r) {
                const int row = brow + wr * 128 + mi * 32 + q * 8 + r + 4 * lh;
                const float sc = scales[row] * ws;
#pragma unroll
                for (int ni = 0; ni < 2; ++ni) {
                    const int col = bcol + wc * 64 + ni * 32 + l31;
                    out[(size_t)row * OUT_F + col] =
                        (float)acc[mi][ni][q * 4 + r] * sc + bias[col];
                }
            }
        }
    }
#undef STAGE
#undef PF
#undef MFMA8
#undef PHASE
#undef BARFENCE
#undef VM0
}

extern "C" void kernel_launch(void* const* d_in, const int* in_sizes, int n_in,
                              void* d_out, int out_size, void* d_ws, size_t ws_size,
                              hipStream_t stream) {
    const float* x       = (const float*)d_in[0];
    const float* w_t     = (const float*)d_in[1];
    const float* w_scale = (const float*)d_in[2];
    const float* bias    = (const float*)d_in[3];
    float* out = (float*)d_out;

    int8_t* xq     = (int8_t*)d_ws;
    float*  scales = (float*)((char*)d_ws + (size_t)T_ROWS * IN_F);
    int8_t* w8     = (int8_t*)((char*)d_ws + (size_t)T_ROWS * IN_F + T_ROWS * sizeof(float));

    prep_kernel<<<T_ROWS + (OUT_F * IN_F) / (16 * 256), 256, 0, stream>>>(
        x, xq, scales, w_t, w8);

    gemm_kernel<<<(T_ROWS / 256) * (OUT_F / 256), 512, 0, stream>>>(
        xq, w8, scales, bias, w_scale, out);
}

// Round 9
// 185.218 us; speedup vs baseline: 1.0393x; 1.0352x over previous
//
#include <hip/hip_runtime.h>
#include <stdint.h>

#define T_ROWS 8192
#define IN_F 4096
#define OUT_F 4096

using i32x4 = __attribute__((ext_vector_type(4))) int;

#define GLOBAL_AS __attribute__((address_space(1)))
#define LDS_AS __attribute__((address_space(3)))

static __device__ __forceinline__ void load_lds16(const void* g, void* l) {
    __builtin_amdgcn_global_load_lds((const GLOBAL_AS uint32_t*)g,
                                     (LDS_AS uint32_t*)l, 16, 0, 0);
}

// -------- Kernel 1: fused prep: per-row int8 quant (blocks 0..8191) +
//                    ternary f32 -> int8 weight pack (blocks 8192..12287) --------
__global__ __launch_bounds__(256) void prep_kernel(const float* __restrict__ x,
                                                   int8_t* __restrict__ xq,
                                                   float* __restrict__ scales,
                                                   const float* __restrict__ w,
                                                   int8_t* __restrict__ w8) {
    if (blockIdx.x < T_ROWS) {
        const int row = blockIdx.x;
        const float* xr = x + (size_t)row * IN_F;
        const float4* xr4 = (const float4*)xr;

        float4 v[4];
        float amax = 0.0f;
#pragma unroll
        for (int i = 0; i < 4; ++i) {
            v[i] = xr4[threadIdx.x + 256 * i];
            amax = fmaxf(amax, fmaxf(fmaxf(fabsf(v[i].x), fabsf(v[i].y)),
                                     fmaxf(fabsf(v[i].z), fabsf(v[i].w))));
        }
#pragma unroll
        for (int off = 32; off; off >>= 1)
            amax = fmaxf(amax, __shfl_xor(amax, off, 64));
        __shared__ float smax[4];
        if ((threadIdx.x & 63) == 0) smax[threadIdx.x >> 6] = amax;
        __syncthreads();
        amax = fmaxf(fmaxf(smax[0], smax[1]), fmaxf(smax[2], smax[3]));

        const float act_scale = fmaxf(amax, 1e-10f) / 127.0f;
        if (threadIdx.x == 0) scales[row] = act_scale;

        int* xqr = (int*)(xq + (size_t)row * IN_F);
#pragma unroll
        for (int i = 0; i < 4; ++i) {
            int q0 = (int)fminf(fmaxf(rintf(v[i].x / act_scale), -127.0f), 127.0f);
            int q1 = (int)fminf(fmaxf(rintf(v[i].y / act_scale), -127.0f), 127.0f);
            int q2 = (int)fminf(fmaxf(rintf(v[i].z / act_scale), -127.0f), 127.0f);
            int q3 = (int)fminf(fmaxf(rintf(v[i].w / act_scale), -127.0f), 127.0f);
            int packed = (q0 & 0xff) | ((q1 & 0xff) << 8) | ((q2 & 0xff) << 16) | (q3 << 24);
            xqr[threadIdx.x + 256 * i] = packed;
        }
    } else {
        const float4* w4 = (const float4*)w;
        int* o4 = (int*)w8;
        size_t base = (size_t)(blockIdx.x - T_ROWS) * 1024 + threadIdx.x;
#pragma unroll
        for (int i = 0; i < 4; ++i) {
            size_t idx = base + 256 * i;
            float4 v = w4[idx];
            int q0 = (int)v.x, q1 = (int)v.y, q2 = (int)v.z, q3 = (int)v.w;
            o4[idx] = (q0 & 0xff) | ((q1 & 0xff) << 8) | ((q2 & 0xff) << 16) | (q3 << 24);
        }
    }
}

// ---------------- Kernel 2: 256x256 8-phase int8 MFMA GEMM (m201-exact) --------
// C[t][o] = sum_k xq[t][k] * w8[o][k]   (NT: both row-major, K contiguous)
// 512 threads = 8 waves (2M x 4N). Per-wave output 128x64 interleaved:
//   rows = m*32 + wr*16 (m=0..7), cols = n*64 + wc*16 (n=0..3).
// LDS: row-major [buf 2][row 256][128B] per matrix (32 KB/buf), XOR-swizzled
// (slot ^= row&7); linear gload_lds dest + pre-swizzled per-lane source
// (rule #21 both-sides). Conflict-free (0 measured, rounds 4-6).
// Phase shape mirrors the verified m201 template EXACTLY:
//   reads(this phase) ; stage ; [lgkmcnt(8) if 12 reads] ; s_barrier ;
//   s_waitcnt lgkmcnt(0) (bare) ; setprio(1) ; 16 MFMA ; setprio(0) ;
//   [vmcnt(6) at p4/p8] ; s_barrier
// Mechanism: reads are issued BEFORE barrier-1, so the shared LDS queue
// drains during the barrier-wait skew (early waves' reads complete while
// late waves finish the previous MFMA block); the post-barrier lgkmcnt(0)
// is then near-instant instead of exposing the full 48-read queue drain.
// The early lgkmcnt(8) on 12-read phases starts the per-wave drain even
// before barrier-1. Correctness: compiler's waitcnt pass independently
// tracks these (pointer-deref) ds_reads into MFMA operands, so the bare
// asm waits are hints, not the safety mechanism. WAR/RAW: reads consumed
// before each phase's barrier-2; restage of any region >=1 barrier later
// (r6 stage slots); vmcnt(6)+barrier at p4/p8 retires the next buffer's
// 8 loads before its first read (same proof as rounds 3-6).
__global__ __launch_bounds__(512, 2) void gemm_kernel(const int8_t* __restrict__ xq,
                                                      const int8_t* __restrict__ w8,
                                                      const float* __restrict__ scales,
                                                      const float* __restrict__ bias,
                                                      const float* __restrict__ wscale_p,
                                                      float* __restrict__ out) {
    __shared__ __align__(16) int8_t As[2 * 256 * 128];  // 64 KiB
    __shared__ __align__(16) int8_t Bs[2 * 256 * 128];  // 64 KiB

    const int tid = threadIdx.x;
    const int lane = tid & 63;
    const int w = tid >> 6;     // wave 0..7
    const int wr = w >> 2;      // 0..1
    const int wc = w & 3;       // 0..3
    const int l16 = lane & 15;
    const int lq = lane >> 4;   // 0..3

    // XCD-aware swizzle: nwg=512 (divisible by 8), contiguous chunk of 64 per XCD.
    int bid = blockIdx.x;
    bid = (bid & 7) * 64 + (bid >> 3);
    const int brow = (bid >> 4) * 256;
    const int bcol = (bid & 15) * 256;

    // per-lane staging source: row +(lane>>3), K-slot (lane&7)^(lane>>3)
    const int lrow = lane >> 3;
    const int lslot = (lane & 7) ^ lrow;
    const int8_t* srcA = xq + (size_t)(brow + lrow) * IN_F + lslot * 16;
    const int8_t* srcB = w8 + (size_t)(bcol + lrow) * IN_F + lslot * 16;

    // per-lane fragment read pointers (ks=0 / ks=1 slots differ by ^4)
    const int sA = l16 & 7;
    const int8_t* pA0 = As + (wr * 16 + l16) * 128 + ((lq ^ sA) << 4);
    const int8_t* pA1 = As + (wr * 16 + l16) * 128 + (((lq ^ sA) ^ 4) << 4);
    const int8_t* pB0 = Bs + (wc * 16 + l16) * 128 + ((lq ^ sA) << 4);
    const int8_t* pB1 = Bs + (wc * 16 + l16) * 128 + (((lq ^ sA) ^ 4) << 4);

// Stage one half-tile (128 rows x 128B) of matrix LDSA from SRC, K-tile KT,
// into buffer BUF. Wave w covers 8-row regions {w, w+8} of the half.
#define STAGE(LDSA, SRC, BUF, H, KT) do {                                          \
    load_lds16((SRC) + (size_t)((H) * 128 + w * 8) * IN_F + (KT) * 128,            \
               (void*)((LDSA) + (BUF) * 32768 + ((H) * 16 + w) * 1024));           \
    load_lds16((SRC) + (size_t)((H) * 128 + (w + 8) * 8) * IN_F + (KT) * 128,      \
               (void*)((LDSA) + (BUF) * 32768 + ((H) * 16 + w + 8) * 1024));       \
} while (0)

#define READ_A(BUF, MH)                                                            \
    _Pragma("unroll") for (int m = 0; m < 4; ++m) {                                \
        ra[m][0] = *(const i32x4*)(pA0 + (BUF) * 32768 + ((MH) * 4 + m) * 4096);   \
        ra[m][1] = *(const i32x4*)(pA1 + (BUF) * 32768 + ((MH) * 4 + m) * 4096);   \
    }

#define READ_B(BUF, NH, RB)                                                        \
    _Pragma("unroll") for (int n = 0; n < 2; ++n) {                                \
        RB[n][0] = *(const i32x4*)(pB0 + (BUF) * 32768 + ((NH) * 2 + n) * 8192);   \
        RB[n][1] = *(const i32x4*)(pB1 + (BUF) * 32768 + ((NH) * 2 + n) * 8192);   \
    }

// m201-exact phase. PRE_STMT = optional early lgkmcnt(8) (12-read phases).
#define PHASE(READS, STAGE_STMT, PRE_STMT, MH, NH, RB, VM_STMT) do {               \
    READS;                                                                         \
    STAGE_STMT;                                                                    \
    PRE_STMT;                                                                      \
    __builtin_amdgcn_s_barrier();                                                  \
    asm volatile("s_waitcnt lgkmcnt(0)");                                          \
    __builtin_amdgcn_s_setprio(1);                                                 \
    _Pragma("unroll") for (int m = 0; m < 4; ++m)                                  \
    _Pragma("unroll") for (int n = 0; n < 2; ++n) {                                \
        acc[(MH) * 4 + m][(NH) * 2 + n] = __builtin_amdgcn_mfma_i32_16x16x64_i8(   \
            ra[m][0], RB[n][0], acc[(MH) * 4 + m][(NH) * 2 + n], 0, 0, 0);         \
        acc[(MH) * 4 + m][(NH) * 2 + n] = __builtin_amdgcn_mfma_i32_16x16x64_i8(   \
            ra[m][1], RB[n][1], acc[(MH) * 4 + m][(NH) * 2 + n], 0, 0, 0);         \
    }                                                                              \
    __builtin_amdgcn_s_setprio(0);                                                 \
    VM_STMT;                                                                       \
    __builtin_amdgcn_s_barrier();                                                  \
} while (0)

#define LGKM8 asm volatile("s_waitcnt lgkmcnt(8)")
#define VM6 asm volatile("s_waitcnt vmcnt(6)" ::: "memory")

    i32x4 acc[8][4] = {};
    i32x4 ra[4][2], rb0[2][2], rb1[2][2];

    // Prologue: buf0 <- K-tile 0 (4 halves), buf1 <- K-tile 1 (A0, B0, B1).
    STAGE(As, srcA, 0, 0, 0);
    STAGE(Bs, srcB, 0, 0, 0);
    STAGE(Bs, srcB, 0, 1, 0);
    STAGE(As, srcA, 0, 1, 0);
    STAGE(As, srcA, 1, 0, 1);
    STAGE(Bs, srcB, 1, 0, 1);
    STAGE(Bs, srcB, 1, 1, 1);
    VM6;  // buf0's 8 loads done
    __builtin_amdgcn_s_barrier();

    for (int t = 0; t < 16; ++t) {
        const int k1 = 2 * t + 1;
        const int k2 = (2 * t + 2) & 31;  // wrap on last iter: dead-but-safe stages
        const int k3 = (2 * t + 3) & 31;
        PHASE(READ_A(0, 0); READ_B(0, 0, rb0), STAGE(As, srcA, 1, 1, k1), LGKM8,
              0, 0, rb0, );
        PHASE(READ_B(0, 1, rb1),               STAGE(As, srcA, 0, 0, k2), ,
              0, 1, rb1, );
        PHASE(READ_A(0, 1),                    STAGE(Bs, srcB, 0, 0, k2), ,
              1, 1, rb1, );
        PHASE(,                                STAGE(Bs, srcB, 0, 1, k2), ,
              1, 0, rb0, VM6);
        PHASE(READ_A(1, 0); READ_B(1, 0, rb0), STAGE(As, srcA, 0, 1, k2), LGKM8,
              0, 0, rb0, );
        PHASE(READ_B(1, 1, rb1),               STAGE(As, srcA, 1, 0, k3), ,
              0, 1, rb1, );
        PHASE(READ_A(1, 1),                    STAGE(Bs, srcB, 1, 0, k3), ,
              1, 1, rb1, );
        PHASE(,                                STAGE(Bs, srcB, 1, 1, k3), ,
              1, 0, rb0, VM6);
    }

    // Epilogue: D mapping col = lane&15, row = lq*4 + j within each 16x16 frag.
    const float ws = wscale_p[0];
#pragma unroll
    for (int m = 0; m < 8; ++m) {
        const int row0 = brow + m * 32 + wr * 16 + lq * 4;
#pragma unroll
        for (int j = 0; j < 4; ++j) {
            const int row = row0 + j;
            const float sc = scales[row] * ws;
#pragma unroll
            for (int n = 0; n < 4; ++n) {
                const int col = bcol + n * 64 + wc * 16 + l16;
                out[(size_t)row * OUT_F + col] = (float)acc[m][n][j] * sc + bias[col];
            }
        }
    }
#undef STAGE
#undef READ_A
#undef READ_B
#undef PHASE
#undef LGKM8
#undef VM6
}

extern "C" void kernel_launch(void* const* d_in, const int* in_sizes, int n_in,
                              void* d_out, int out_size, void* d_ws, size_t ws_size,
                              hipStream_t stream) {
    const float* x       = (const float*)d_in[0];
    const float* w_t     = (const float*)d_in[1];
    const float* w_scale = (const float*)d_in[2];
    const float* bias    = (const float*)d_in[3];
    float* out = (float*)d_out;

    int8_t* xq     = (int8_t*)d_ws;
    float*  scales = (float*)((char*)d_ws + (size_t)T_ROWS * IN_F);
    int8_t* w8     = (int8_t*)((char*)d_ws + (size_t)T_ROWS * IN_F + T_ROWS * sizeof(float));

    prep_kernel<<<T_ROWS + (OUT_F * IN_F) / (16 * 256), 256, 0, stream>>>(
        x, xq, scales, w_t, w8);

    gemm_kernel<<<(T_ROWS / 256) * (OUT_F / 256), 512, 0, stream>>>(
        xq, w8, scales, bias, w_scale, out);
}